// Round 1
// baseline (36880.463 us; speedup 1.0000x reference)
//
#include <hip/hip_runtime.h>
#include <hip/hip_cooperative_groups.h>

namespace cg = cooperative_groups;

#define BB 128
#define TT 1024
#define II 256
#define HH 512
#define OO 256
#define KK 768          // I + H
#define LDK 776         // padded LDS row stride in bf16 elems (kills b128 bank conflicts)
#define GB 4            // batch groups
#define GH 64           // hidden groups
#define RPW 32          // rows per WG   (BB/GB)
#define UPW 8           // hidden units per WG (HH/GH)
#define NC 32           // gate-cols per WG (4 gates * UPW)

typedef short bf16x8 __attribute__((ext_vector_type(8)));
typedef float f32x4 __attribute__((ext_vector_type(4)));

__device__ __forceinline__ unsigned short f2bf(float f) {
  unsigned int u = __builtin_bit_cast(unsigned int, f);
  unsigned int r = (u + 0x7fffu + ((u >> 16) & 1u)) >> 16;
  return (unsigned short)r;
}
__device__ __forceinline__ float bf2f(unsigned short h) {
  unsigned int u = ((unsigned int)h) << 16;
  return __builtin_bit_cast(float, u);
}
__device__ __forceinline__ float sigm(float x) { return 1.0f / (1.0f + expf(-x)); }

// Persistent cooperative LSTM kernel.
// grid = 256 WGs (GB=4 batch-groups x GH=64 hidden-groups), block = 256 threads.
// WG (gb,gh): rows gb*32..+32, hidden units gh*8..+8 (all 4 gates).
// Weight slice resident in LDS as split bf16 (hi+lo) for ~fp32 weight accuracy.
// Cell state C lives in registers (1 float per thread). h broadcast via global bf16,
// double-buffered -> ONE grid.sync() per timestep.
__global__ void __launch_bounds__(256, 1)
lstm_kernel(const float* __restrict__ x,
            const float* __restrict__ Wf, const float* __restrict__ bfp,
            const float* __restrict__ Wi, const float* __restrict__ bip,
            const float* __restrict__ Wc, const float* __restrict__ bcp,
            const float* __restrict__ Wo, const float* __restrict__ bop,
            const float* __restrict__ Wlin, const float* __restrict__ blin,
            float* __restrict__ out,
            unsigned short* __restrict__ hbuf,   // [2][BB][HH] bf16
            float* __restrict__ hT)              // [BB][HH] f32
{
  extern __shared__ char smem[];
  unsigned short* Whi = (unsigned short*)smem;          // [NC][LDK]
  unsigned short* Wlo = Whi + NC * LDK;                 // [NC][LDK]
  unsigned short* Ab  = Wlo + NC * LDK;                 // [RPW][LDK]  (cols 0..255 = x, 256..767 = h)
  float* pre = (float*)(Ab + RPW * LDK);                // [32][33] preacts (+final-linear h staging)

  const int gid = blockIdx.x;
  const int gb = gid >> 6;       // 0..3
  const int gh = gid & 63;       // 0..63
  const int tid = threadIdx.x;   // 0..255

  // ---- one-time: load weight slice, split into hi+lo bf16 ----
  {
    const float* Wg[4] = {Wf, Wi, Wc, Wo};
    int row32 = tid >> 3;              // 0..31 == g*8+u == LDS col index
    int g = row32 >> 3, u = row32 & 7;
    int k0 = (tid & 7) * 96;
    const float* src = Wg[g] + (size_t)(gh * UPW + u) * KK + k0;
    unsigned short* dhi = Whi + row32 * LDK + k0;
    unsigned short* dlo = Wlo + row32 * LDK + k0;
#pragma unroll
    for (int j = 0; j < 96; j += 4) {
      float4 v = *(const float4*)(src + j);
      float vv[4] = {v.x, v.y, v.z, v.w};
#pragma unroll
      for (int c = 0; c < 4; ++c) {
        unsigned short hi = f2bf(vv[c]);
        unsigned short lo = f2bf(vv[c] - bf2f(hi));
        dhi[j + c] = hi;
        dlo[j + c] = lo;
      }
    }
  }

  // ---- one-time: zero h_0 (this WG's owned slice), init C, biases ----
  {
    int row = tid >> 3, u = tid & 7;
    hbuf[(size_t)(gb * RPW + row) * HH + gh * UPW + u] = 0;  // buffer 0
  }
  const int uu = tid & 7;
  const int ucol = gh * UPW + uu;
  const float bfv = bfp[ucol], biv = bip[ucol], bcv = bcp[ucol], bov = bop[ucol];
  float C = 0.0f;

  const int wave = tid >> 6, lane = tid & 63;
  const int wm = wave >> 1, wn = wave & 1;
  const int ra = wm * 16 + (lane & 15);         // A row (0..31)
  const int rb = wn * 16 + (lane & 15);         // B col (0..31)
  const int kq = (lane >> 4) * 8;               // k sub-offset
  const int dcol = wn * 16 + (lane & 15);       // D col
  const int dr0 = wm * 16 + ((lane >> 4) << 2); // D row base

  cg::grid_group grid = cg::this_grid();
  grid.sync();

  // ================= time loop =================
  for (int t = 0; t < TT; ++t) {
    const int cur = t & 1, nxt = cur ^ 1;

    // stage x_t (fp32 -> bf16) into A cols 0..255
    {
      int row = tid >> 3, c0 = (tid & 7) * 32;
      const float4* src = (const float4*)(x + ((size_t)(gb * RPW + row) * TT + t) * II + c0);
      unsigned short* dst = Ab + row * LDK + c0;
#pragma unroll
      for (int j = 0; j < 8; ++j) {
        float4 v = src[j];
        ushort4 s;
        s.x = f2bf(v.x); s.y = f2bf(v.y); s.z = f2bf(v.z); s.w = f2bf(v.w);
        *(ushort4*)(dst + 4 * j) = s;
      }
    }
    // stage h_t (bf16) into A cols 256..767
    {
      int row = tid >> 3, c0 = (tid & 7) * 64;
      const uint4* src = (const uint4*)(hbuf + (size_t)cur * BB * HH +
                                        (size_t)(gb * RPW + row) * HH + c0);
      uint4* dst = (uint4*)(Ab + row * LDK + II + c0);
#pragma unroll
      for (int j = 0; j < 8; ++j) dst[j] = src[j];
    }
    __syncthreads();

    // MFMA: preact[32x32] = A[32x768] * W^T, weights split hi+lo
    f32x4 acc = {0.f, 0.f, 0.f, 0.f};
#pragma unroll
    for (int ks = 0; ks < 24; ++ks) {
      int k = ks * 32 + kq;
      bf16x8 a  = *(const bf16x8*)(Ab  + ra * LDK + k);
      bf16x8 bh = *(const bf16x8*)(Whi + rb * LDK + k);
      bf16x8 bl = *(const bf16x8*)(Wlo + rb * LDK + k);
      acc = __builtin_amdgcn_mfma_f32_16x16x32_bf16(a, bh, acc, 0, 0, 0);
      acc = __builtin_amdgcn_mfma_f32_16x16x32_bf16(a, bl, acc, 0, 0, 0);
    }
#pragma unroll
    for (int r = 0; r < 4; ++r) pre[(dr0 + r) * 33 + dcol] = acc[r];
    __syncthreads();

    // gate nonlinearities + state update (thread owns (row,u))
    {
      int row = tid >> 3;
      float pf = pre[row * 33 + uu]      + bfv;
      float pi = pre[row * 33 + 8 + uu]  + biv;
      float pc = pre[row * 33 + 16 + uu] + bcv;
      float po = pre[row * 33 + 24 + uu] + bov;
      float fg = sigm(pf), ig = sigm(pi), cg_ = tanhf(pc), og = sigm(po);
      C = fg * C + ig * cg_;
      float hn = og * tanhf(C);
      size_t gi = (size_t)(gb * RPW + row) * HH + gh * UPW + uu;
      hbuf[(size_t)nxt * BB * HH + gi] = f2bf(hn);
      if (t == TT - 1) hT[gi] = hn;
    }
    grid.sync();
  }

  // ================= final linear: out = h_T @ W_lin^T + b_lin =================
  // WG gid covers flat outputs [gid*128, gid*128+128): b = gid>>1, o-half = gid&1
  {
    int b = gid >> 1;
    int o0 = (gid & 1) * 128;
    float* hs = pre;  // reuse LDS (2 KB)
    if (tid < 128) ((float4*)hs)[tid] = *(const float4*)(hT + (size_t)b * HH + tid * 4);
    __syncthreads();
    if (tid < 128) {
      int o = o0 + tid;
      float a2 = blin[o];
      const float4* wr = (const float4*)(Wlin + (size_t)o * HH);
#pragma unroll 4
      for (int j = 0; j < 128; ++j) {
        float4 wv = wr[j];
        a2 += wv.x * hs[4 * j] + wv.y * hs[4 * j + 1] + wv.z * hs[4 * j + 2] + wv.w * hs[4 * j + 3];
      }
      out[(size_t)b * OO + o] = a2;
    }
  }
}

extern "C" void kernel_launch(void* const* d_in, const int* in_sizes, int n_in,
                              void* d_out, int out_size, void* d_ws, size_t ws_size,
                              hipStream_t stream) {
  const float* x    = (const float*)d_in[0];
  const float* Wf   = (const float*)d_in[1];
  const float* bf_  = (const float*)d_in[2];
  const float* Wi   = (const float*)d_in[3];
  const float* bi_  = (const float*)d_in[4];
  const float* Wc   = (const float*)d_in[5];
  const float* bc_  = (const float*)d_in[6];
  const float* Wo   = (const float*)d_in[7];
  const float* bo_  = (const float*)d_in[8];
  const float* Wlin = (const float*)d_in[9];
  const float* blin = (const float*)d_in[10];
  float* out = (float*)d_out;

  unsigned short* hbuf = (unsigned short*)d_ws;                      // 2*128*512*2 = 256 KB
  float* hT = (float*)((char*)d_ws + (size_t)2 * BB * HH * 2);       // 256 KB

  const unsigned smem = (3 * NC * LDK) * 2 + 32 * 33 * 4;            // 153,216 B
  hipFuncSetAttribute((const void*)lstm_kernel,
                      hipFuncAttributeMaxDynamicSharedMemorySize, (int)smem);

  void* args[] = {(void*)&x,  (void*)&Wf, (void*)&bf_, (void*)&Wi, (void*)&bi_,
                  (void*)&Wc, (void*)&bc_, (void*)&Wo, (void*)&bo_,
                  (void*)&Wlin, (void*)&blin, (void*)&out, (void*)&hbuf, (void*)&hT};
  hipLaunchCooperativeKernel((const void*)lstm_kernel, dim3(256), dim3(256),
                             args, smem, stream);
}

// Round 4
// 11698.130 us; speedup vs baseline: 3.1527x; 3.1527x over previous
//
#include <hip/hip_runtime.h>

#define BB 128
#define TT 1024
#define II 256
#define HH 512
#define OO 256
#define KK 768

typedef _Float16 half8 __attribute__((ext_vector_type(8)));
typedef float f32x4 __attribute__((ext_vector_type(4)));

__device__ __forceinline__ float sigm(float x) { return 1.f / (1.f + __expf(-x)); }
__device__ __forceinline__ float tanhfast(float x) {
  float e = __expf(-2.f * fabsf(x));
  return copysignf((1.f - e) / (1.f + e), x);
}

// One LSTM timestep. Grid 256 WGs (4 batch-groups x 64 hidden-groups), 256 thr.
// WG (gb,gh): batch rows gb*32..+32, hidden units gh*8..+8 (32 gate-cols).
// Weights re-read from L2 (XCD-resident, same lines every step) as fp32,
// converted to fp16 in-flight; activations fp16; accum/state fp32.
// Cross-step h/C visibility via kernel launch boundaries (bedrock semantics).
__global__ void __launch_bounds__(256)
lstm_step(const float* __restrict__ x,
          const float* __restrict__ Wf, const float* __restrict__ Wi,
          const float* __restrict__ Wc, const float* __restrict__ Wo,
          const float* __restrict__ bfp, const float* __restrict__ bip,
          const float* __restrict__ bcp, const float* __restrict__ bop,
          _Float16* __restrict__ hbuf,  // [2][BB][HH] fp16
          float* __restrict__ Cws,      // [BB][HH] fp32
          int t)
{
  __shared__ float pre[32 * 33];

  const int gid = blockIdx.x;
  const int gb = gid >> 6, gh = gid & 63;
  const int tid = threadIdx.x;
  const int wave = tid >> 6, lane = tid & 63;
  const int wm = wave >> 1, wn = wave & 1;
  const int r = lane & 15, q = lane >> 4;

  const int brow = gb * 32 + wm * 16 + r;  // A (batch) row this lane feeds
  const int cc = wn * 16 + r;              // B col 0..31 = gate*8 + unit
  const int g = cc >> 3, u = cc & 7;

  const float* Wg = (g == 0) ? Wf : (g == 1) ? Wi : (g == 2) ? Wc : Wo;
  const float* wsrc = Wg + (size_t)(gh * 8 + u) * KK + q * 8;
  const float* xp = x + ((size_t)brow * TT + t) * II + q * 8;
  const _Float16* hp = hbuf + (size_t)(t & 1) * BB * HH + (size_t)brow * HH + q * 8;

  f32x4 acc = {0.f, 0.f, 0.f, 0.f};

  // x part: ks 0..8 (fp32 -> fp16 convert for both W and x)
#pragma unroll
  for (int ks = 0; ks < 8; ++ks) {
    float4 w0 = *(const float4*)(wsrc + ks * 32);
    float4 w1 = *(const float4*)(wsrc + ks * 32 + 4);
    float4 a0 = *(const float4*)(xp + ks * 32);
    float4 a1 = *(const float4*)(xp + ks * 32 + 4);
    half8 wf, af;
    wf[0] = (_Float16)w0.x; wf[1] = (_Float16)w0.y; wf[2] = (_Float16)w0.z; wf[3] = (_Float16)w0.w;
    wf[4] = (_Float16)w1.x; wf[5] = (_Float16)w1.y; wf[6] = (_Float16)w1.z; wf[7] = (_Float16)w1.w;
    af[0] = (_Float16)a0.x; af[1] = (_Float16)a0.y; af[2] = (_Float16)a0.z; af[3] = (_Float16)a0.w;
    af[4] = (_Float16)a1.x; af[5] = (_Float16)a1.y; af[6] = (_Float16)a1.z; af[7] = (_Float16)a1.w;
    acc = __builtin_amdgcn_mfma_f32_16x16x32_f16(af, wf, acc, 0, 0, 0);
  }

  // h part: ks 8..24 (h already fp16; skip entirely at t==0 since h_0 = 0)
  if (t > 0) {
#pragma unroll
    for (int ks = 0; ks < 16; ++ks) {
      float4 w0 = *(const float4*)(wsrc + (8 + ks) * 32);
      float4 w1 = *(const float4*)(wsrc + (8 + ks) * 32 + 4);
      half8 wf;
      wf[0] = (_Float16)w0.x; wf[1] = (_Float16)w0.y; wf[2] = (_Float16)w0.z; wf[3] = (_Float16)w0.w;
      wf[4] = (_Float16)w1.x; wf[5] = (_Float16)w1.y; wf[6] = (_Float16)w1.z; wf[7] = (_Float16)w1.w;
      half8 af = *(const half8*)(hp + ks * 32);
      acc = __builtin_amdgcn_mfma_f32_16x16x32_f16(af, wf, acc, 0, 0, 0);
    }
  }

  // D layout (m89): col = lane&15, row = (lane>>4)*4 + i  (within 16x16 tile)
#pragma unroll
  for (int i = 0; i < 4; ++i)
    pre[(wm * 16 + q * 4 + i) * 33 + wn * 16 + r] = acc[i];
  __syncthreads();

  // gates + state update: thread owns (row=tid>>3, unit=tid&7)
  {
    const int grow = tid >> 3, gu = tid & 7;
    const int gcol = gh * 8 + gu;
    float pf = pre[grow * 33 + gu]      + bfp[gcol];
    float pi = pre[grow * 33 + 8 + gu]  + bip[gcol];
    float pc = pre[grow * 33 + 16 + gu] + bcp[gcol];
    float po = pre[grow * 33 + 24 + gu] + bop[gcol];
    float fg = sigm(pf), ig = sigm(pi), og = sigm(po);
    float cg = tanhfast(pc);
    size_t gi = (size_t)(gb * 32 + grow) * HH + gh * 8 + gu;
    float Cold = (t > 0) ? Cws[gi] : 0.f;  // t==0: poison-immune init
    float C = fg * Cold + ig * cg;
    Cws[gi] = C;
    hbuf[(size_t)((t + 1) & 1) * BB * HH + gi] = (_Float16)(og * tanhfast(C));
  }
}

// out = h_T @ W_lin^T + b_lin.  WG per (batch row, output half).
__global__ void __launch_bounds__(256)
lstm_out(const _Float16* __restrict__ hbuf,  // buffer 0 holds h_T (TT even)
         const float* __restrict__ Wlin, const float* __restrict__ blin,
         float* __restrict__ out)
{
  __shared__ float hs[HH];
  const int b = blockIdx.x >> 1;
  const int o0 = (blockIdx.x & 1) * 128;
  const int tid = threadIdx.x;
  hs[2 * tid]     = (float)hbuf[(size_t)b * HH + 2 * tid];
  hs[2 * tid + 1] = (float)hbuf[(size_t)b * HH + 2 * tid + 1];
  __syncthreads();
  if (tid < 128) {
    int o = o0 + tid;
    float a2 = blin[o];
    const float4* wr = (const float4*)(Wlin + (size_t)o * HH);
#pragma unroll 4
    for (int j = 0; j < 128; ++j) {
      float4 wv = wr[j];
      a2 += wv.x * hs[4 * j] + wv.y * hs[4 * j + 1] +
            wv.z * hs[4 * j + 2] + wv.w * hs[4 * j + 3];
    }
    out[(size_t)b * OO + o] = a2;
  }
}

extern "C" void kernel_launch(void* const* d_in, const int* in_sizes, int n_in,
                              void* d_out, int out_size, void* d_ws, size_t ws_size,
                              hipStream_t stream) {
  const float* x    = (const float*)d_in[0];
  const float* Wf   = (const float*)d_in[1];
  const float* bf_  = (const float*)d_in[2];
  const float* Wi   = (const float*)d_in[3];
  const float* bi_  = (const float*)d_in[4];
  const float* Wc   = (const float*)d_in[5];
  const float* bc_  = (const float*)d_in[6];
  const float* Wo   = (const float*)d_in[7];
  const float* bo_  = (const float*)d_in[8];
  const float* Wlin = (const float*)d_in[9];
  const float* blin = (const float*)d_in[10];
  float* out = (float*)d_out;

  _Float16* hbuf = (_Float16*)d_ws;                                // 256 KB
  float* Cws = (float*)((char*)d_ws + (size_t)2 * BB * HH * 2);    // 256 KB

  for (int t = 0; t < TT; ++t)
    lstm_step<<<dim3(256), dim3(256), 0, stream>>>(x, Wf, Wi, Wc, Wo,
                                                   bf_, bi_, bc_, bo_,
                                                   hbuf, Cws, t);
  lstm_out<<<dim3(256), dim3(256), 0, stream>>>(hbuf, Wlin, blin, out);
}

// Round 5
// 6549.908 us; speedup vs baseline: 5.6307x; 1.7860x over previous
//
#include <hip/hip_runtime.h>

#define BB 128
#define TT 1024
#define II 256
#define HH 512
#define OO 256
#define KK 768

typedef _Float16 half8 __attribute__((ext_vector_type(8)));
typedef _Float16 half4v __attribute__((ext_vector_type(4)));
typedef float f32x4 __attribute__((ext_vector_type(4)));

__device__ __forceinline__ float sigm(float x) { return 1.f / (1.f + __expf(-x)); }
__device__ __forceinline__ float tanhfast(float x) {
  float e = __expf(-2.f * fabsf(x));
  return copysignf((1.f - e) / (1.f + e), x);
}

// ---------- one-time: W (4x [512,768] fp32) -> fp16 fragment-linear ----------
// W16 index: (((gh*2+wn)*24 + ks)*64 + lane)*8 ; lane r=lane&15 picks gate-col
// c=wn*16+r (g=c>>3 selects gate matrix, u=c&7), q=lane>>4 picks k sub-block.
__global__ void __launch_bounds__(64)
prep_w(const float* __restrict__ Wf, const float* __restrict__ Wi,
       const float* __restrict__ Wc, const float* __restrict__ Wo,
       _Float16* __restrict__ W16)
{
  const int bid = blockIdx.x;          // (gh*2+wn)*24 + ks
  const int ks = bid % 24;
  const int gw = bid / 24;
  const int wn = gw & 1, gh = gw >> 1;
  const int lane = threadIdx.x;
  const int r = lane & 15, q = lane >> 4;
  const int c = wn * 16 + r;
  const int g = c >> 3, u = c & 7;
  const float* Wg = (g == 0) ? Wf : (g == 1) ? Wi : (g == 2) ? Wc : Wo;
  const float* src = Wg + (size_t)(gh * 8 + u) * KK + ks * 32 + q * 8;
  float4 w0 = *(const float4*)src;
  float4 w1 = *(const float4*)(src + 4);
  half8 h;
  h[0] = (_Float16)w0.x; h[1] = (_Float16)w0.y; h[2] = (_Float16)w0.z; h[3] = (_Float16)w0.w;
  h[4] = (_Float16)w1.x; h[5] = (_Float16)w1.y; h[6] = (_Float16)w1.z; h[7] = (_Float16)w1.w;
  *(half8*)(W16 + ((size_t)bid * 64 + lane) * 8) = h;
}

// ---------- one-time: x [B][T][I] fp32 -> x16 [T][B][I] fp16 ----------
__global__ void __launch_bounds__(64)
prep_x(const float* __restrict__ x, _Float16* __restrict__ x16)
{
  const int bid = blockIdx.x;          // t*BB + b
  const int b = bid & (BB - 1), t = bid >> 7;
  const int tid = threadIdx.x;
  float4 v = *(const float4*)(x + ((size_t)b * TT + t) * II + tid * 4);
  half4v h;
  h[0] = (_Float16)v.x; h[1] = (_Float16)v.y; h[2] = (_Float16)v.z; h[3] = (_Float16)v.w;
  *(half4v*)(x16 + (size_t)bid * II + tid * 4) = h;
}

// ---------- per-step kernel, path A: fp16 W16 + fp16 x16 ----------
// Grid 256 (4 batch-groups x 64 hidden-groups), block 256 (4 waves).
// Inner loop: 24 x {16B A-load, 16B B-load, MFMA}. No converts.
__global__ void __launch_bounds__(256)
lstm_stepA(const _Float16* __restrict__ W16, const _Float16* __restrict__ x16,
           const float* __restrict__ bfp, const float* __restrict__ bip,
           const float* __restrict__ bcp, const float* __restrict__ bop,
           _Float16* __restrict__ hbuf, float* __restrict__ Cws, int t)
{
  __shared__ float pre[32 * 33];
  const int gid = blockIdx.x;
  const int gb = gid >> 6, gh = gid & 63;
  const int tid = threadIdx.x;
  const int wave = tid >> 6, lane = tid & 63;
  const int wm = wave >> 1, wn = wave & 1;
  const int r = lane & 15, q = lane >> 4;
  const int brow = gb * 32 + wm * 16 + r;

  const half8* wp = (const half8*)W16 + ((size_t)(gh * 2 + wn) * 24) * 64 + lane;
  const _Float16* xr = x16 + ((size_t)t * BB + brow) * II;
  const _Float16* hb = hbuf + (size_t)(t & 1) * BB * HH + (size_t)brow * HH;

  f32x4 acc = {0.f, 0.f, 0.f, 0.f};
#pragma unroll
  for (int ks = 0; ks < 8; ++ks) {
    half8 a = *(const half8*)(xr + ks * 32 + q * 8);
    acc = __builtin_amdgcn_mfma_f32_16x16x32_f16(a, wp[ks * 64], acc, 0, 0, 0);
  }
  if (t > 0) {
#pragma unroll
    for (int ks = 0; ks < 16; ++ks) {
      half8 a = *(const half8*)(hb + ks * 32 + q * 8);
      acc = __builtin_amdgcn_mfma_f32_16x16x32_f16(a, wp[(8 + ks) * 64], acc, 0, 0, 0);
    }
  }
#pragma unroll
  for (int i = 0; i < 4; ++i)
    pre[(wm * 16 + q * 4 + i) * 33 + wn * 16 + r] = acc[i];
  __syncthreads();
  {
    const int grow = tid >> 3, gu = tid & 7;
    const int gcol = gh * 8 + gu;
    float pf = pre[grow * 33 + gu]      + bfp[gcol];
    float pi = pre[grow * 33 + 8 + gu]  + bip[gcol];
    float pc = pre[grow * 33 + 16 + gu] + bcp[gcol];
    float po = pre[grow * 33 + 24 + gu] + bop[gcol];
    float fg = sigm(pf), ig = sigm(pi), og = sigm(po);
    float cg = tanhfast(pc);
    size_t gi = (size_t)(gb * 32 + grow) * HH + gh * 8 + gu;
    float Cold = (t > 0) ? Cws[gi] : 0.f;
    float C = fg * Cold + ig * cg;
    Cws[gi] = C;
    hbuf[(size_t)((t + 1) & 1) * BB * HH + gi] = (_Float16)(og * tanhfast(C));
  }
}

// ---------- per-step kernel, path B: fp16 W16 + fp32 x direct ----------
__global__ void __launch_bounds__(256)
lstm_stepB(const _Float16* __restrict__ W16, const float* __restrict__ x,
           const float* __restrict__ bfp, const float* __restrict__ bip,
           const float* __restrict__ bcp, const float* __restrict__ bop,
           _Float16* __restrict__ hbuf, float* __restrict__ Cws, int t)
{
  __shared__ float pre[32 * 33];
  const int gid = blockIdx.x;
  const int gb = gid >> 6, gh = gid & 63;
  const int tid = threadIdx.x;
  const int wave = tid >> 6, lane = tid & 63;
  const int wm = wave >> 1, wn = wave & 1;
  const int r = lane & 15, q = lane >> 4;
  const int brow = gb * 32 + wm * 16 + r;

  const half8* wp = (const half8*)W16 + ((size_t)(gh * 2 + wn) * 24) * 64 + lane;
  const float* xp = x + ((size_t)brow * TT + t) * II + q * 8;
  const _Float16* hb = hbuf + (size_t)(t & 1) * BB * HH + (size_t)brow * HH;

  f32x4 acc = {0.f, 0.f, 0.f, 0.f};
#pragma unroll
  for (int ks = 0; ks < 8; ++ks) {
    float4 a0 = *(const float4*)(xp + ks * 32);
    float4 a1 = *(const float4*)(xp + ks * 32 + 4);
    half8 a;
    a[0] = (_Float16)a0.x; a[1] = (_Float16)a0.y; a[2] = (_Float16)a0.z; a[3] = (_Float16)a0.w;
    a[4] = (_Float16)a1.x; a[5] = (_Float16)a1.y; a[6] = (_Float16)a1.z; a[7] = (_Float16)a1.w;
    acc = __builtin_amdgcn_mfma_f32_16x16x32_f16(a, wp[ks * 64], acc, 0, 0, 0);
  }
  if (t > 0) {
#pragma unroll
    for (int ks = 0; ks < 16; ++ks) {
      half8 a = *(const half8*)(hb + ks * 32 + q * 8);
      acc = __builtin_amdgcn_mfma_f32_16x16x32_f16(a, wp[(8 + ks) * 64], acc, 0, 0, 0);
    }
  }
#pragma unroll
  for (int i = 0; i < 4; ++i)
    pre[(wm * 16 + q * 4 + i) * 33 + wn * 16 + r] = acc[i];
  __syncthreads();
  {
    const int grow = tid >> 3, gu = tid & 7;
    const int gcol = gh * 8 + gu;
    float pf = pre[grow * 33 + gu]      + bfp[gcol];
    float pi = pre[grow * 33 + 8 + gu]  + bip[gcol];
    float pc = pre[grow * 33 + 16 + gu] + bcp[gcol];
    float po = pre[grow * 33 + 24 + gu] + bop[gcol];
    float fg = sigm(pf), ig = sigm(pi), og = sigm(po);
    float cg = tanhfast(pc);
    size_t gi = (size_t)(gb * 32 + grow) * HH + gh * 8 + gu;
    float Cold = (t > 0) ? Cws[gi] : 0.f;
    float C = fg * Cold + ig * cg;
    Cws[gi] = C;
    hbuf[(size_t)((t + 1) & 1) * BB * HH + gi] = (_Float16)(og * tanhfast(C));
  }
}

// ---------- per-step kernel, path C: R4 fallback (fp32 W direct) ----------
__global__ void __launch_bounds__(256)
lstm_stepC(const float* __restrict__ x,
           const float* __restrict__ Wf, const float* __restrict__ Wi,
           const float* __restrict__ Wc, const float* __restrict__ Wo,
           const float* __restrict__ bfp, const float* __restrict__ bip,
           const float* __restrict__ bcp, const float* __restrict__ bop,
           _Float16* __restrict__ hbuf, float* __restrict__ Cws, int t)
{
  __shared__ float pre[32 * 33];
  const int gid = blockIdx.x;
  const int gb = gid >> 6, gh = gid & 63;
  const int tid = threadIdx.x;
  const int wave = tid >> 6, lane = tid & 63;
  const int wm = wave >> 1, wn = wave & 1;
  const int r = lane & 15, q = lane >> 4;
  const int brow = gb * 32 + wm * 16 + r;
  const int cc = wn * 16 + r;
  const int g = cc >> 3, u = cc & 7;
  const float* Wg = (g == 0) ? Wf : (g == 1) ? Wi : (g == 2) ? Wc : Wo;
  const float* wsrc = Wg + (size_t)(gh * 8 + u) * KK + q * 8;
  const float* xp = x + ((size_t)brow * TT + t) * II + q * 8;
  const _Float16* hp = hbuf + (size_t)(t & 1) * BB * HH + (size_t)brow * HH + q * 8;

  f32x4 acc = {0.f, 0.f, 0.f, 0.f};
#pragma unroll
  for (int ks = 0; ks < 8; ++ks) {
    float4 w0 = *(const float4*)(wsrc + ks * 32);
    float4 w1 = *(const float4*)(wsrc + ks * 32 + 4);
    float4 a0 = *(const float4*)(xp + ks * 32);
    float4 a1 = *(const float4*)(xp + ks * 32 + 4);
    half8 wf, af;
    wf[0] = (_Float16)w0.x; wf[1] = (_Float16)w0.y; wf[2] = (_Float16)w0.z; wf[3] = (_Float16)w0.w;
    wf[4] = (_Float16)w1.x; wf[5] = (_Float16)w1.y; wf[6] = (_Float16)w1.z; wf[7] = (_Float16)w1.w;
    af[0] = (_Float16)a0.x; af[1] = (_Float16)a0.y; af[2] = (_Float16)a0.z; af[3] = (_Float16)a0.w;
    af[4] = (_Float16)a1.x; af[5] = (_Float16)a1.y; af[6] = (_Float16)a1.z; af[7] = (_Float16)a1.w;
    acc = __builtin_amdgcn_mfma_f32_16x16x32_f16(af, wf, acc, 0, 0, 0);
  }
  if (t > 0) {
#pragma unroll
    for (int ks = 0; ks < 16; ++ks) {
      float4 w0 = *(const float4*)(wsrc + (8 + ks) * 32);
      float4 w1 = *(const float4*)(wsrc + (8 + ks) * 32 + 4);
      half8 wf;
      wf[0] = (_Float16)w0.x; wf[1] = (_Float16)w0.y; wf[2] = (_Float16)w0.z; wf[3] = (_Float16)w0.w;
      wf[4] = (_Float16)w1.x; wf[5] = (_Float16)w1.y; wf[6] = (_Float16)w1.z; wf[7] = (_Float16)w1.w;
      half8 af = *(const half8*)(hp + ks * 32);
      acc = __builtin_amdgcn_mfma_f32_16x16x32_f16(af, wf, acc, 0, 0, 0);
    }
  }
#pragma unroll
  for (int i = 0; i < 4; ++i)
    pre[(wm * 16 + q * 4 + i) * 33 + wn * 16 + r] = acc[i];
  __syncthreads();
  {
    const int grow = tid >> 3, gu = tid & 7;
    const int gcol = gh * 8 + gu;
    float pf = pre[grow * 33 + gu]      + bfp[gcol];
    float pi = pre[grow * 33 + 8 + gu]  + bip[gcol];
    float pc = pre[grow * 33 + 16 + gu] + bcp[gcol];
    float po = pre[grow * 33 + 24 + gu] + bop[gcol];
    float fg = sigm(pf), ig = sigm(pi), og = sigm(po);
    float cg = tanhfast(pc);
    size_t gi = (size_t)(gb * 32 + grow) * HH + gh * 8 + gu;
    float Cold = (t > 0) ? Cws[gi] : 0.f;
    float C = fg * Cold + ig * cg;
    Cws[gi] = C;
    hbuf[(size_t)((t + 1) & 1) * BB * HH + gi] = (_Float16)(og * tanhfast(C));
  }
}

// ---------- epilogue: out = h_T @ W_lin^T + b_lin ----------
__global__ void __launch_bounds__(256)
lstm_out(const _Float16* __restrict__ hbuf,  // buffer 0 holds h_T (TT even)
         const float* __restrict__ Wlin, const float* __restrict__ blin,
         float* __restrict__ out)
{
  __shared__ float hs[HH];
  const int b = blockIdx.x >> 1;
  const int o0 = (blockIdx.x & 1) * 128;
  const int tid = threadIdx.x;
  hs[2 * tid]     = (float)hbuf[(size_t)b * HH + 2 * tid];
  hs[2 * tid + 1] = (float)hbuf[(size_t)b * HH + 2 * tid + 1];
  __syncthreads();
  if (tid < 128) {
    int o = o0 + tid;
    float a2 = blin[o];
    const float4* wr = (const float4*)(Wlin + (size_t)o * HH);
#pragma unroll 4
    for (int j = 0; j < 128; ++j) {
      float4 wv = wr[j];
      a2 += wv.x * hs[4 * j] + wv.y * hs[4 * j + 1] +
            wv.z * hs[4 * j + 2] + wv.w * hs[4 * j + 3];
    }
    out[(size_t)b * OO + o] = a2;
  }
}

extern "C" void kernel_launch(void* const* d_in, const int* in_sizes, int n_in,
                              void* d_out, int out_size, void* d_ws, size_t ws_size,
                              hipStream_t stream) {
  const float* x    = (const float*)d_in[0];
  const float* Wf   = (const float*)d_in[1];
  const float* bf_  = (const float*)d_in[2];
  const float* Wi   = (const float*)d_in[3];
  const float* bi_  = (const float*)d_in[4];
  const float* Wc   = (const float*)d_in[5];
  const float* bc_  = (const float*)d_in[6];
  const float* Wo   = (const float*)d_in[7];
  const float* bo_  = (const float*)d_in[8];
  const float* Wlin = (const float*)d_in[9];
  const float* blin = (const float*)d_in[10];
  float* out = (float*)d_out;

  // ws layout (path A): W16 [0,3145728) | hbuf [3145728,3407872) |
  //                     Cws [3407872,3932160) | x16 [4194304, 71303168)
  const size_t offH = 3145728, offC = 3407872, offX = 4194304;
  const size_t needA = offX + (size_t)TT * BB * II * 2;   // 71,303,168
  const size_t needB = 3932160;

  if (ws_size >= needA) {
    _Float16* W16  = (_Float16*)d_ws;
    _Float16* hbuf = (_Float16*)((char*)d_ws + offH);
    float*    Cws  = (float*)((char*)d_ws + offC);
    _Float16* x16  = (_Float16*)((char*)d_ws + offX);
    prep_w<<<dim3(64 * 2 * 24), dim3(64), 0, stream>>>(Wf, Wi, Wc, Wo, W16);
    prep_x<<<dim3(TT * BB), dim3(64), 0, stream>>>(x, x16);
    for (int t = 0; t < TT; ++t)
      lstm_stepA<<<dim3(256), dim3(256), 0, stream>>>(W16, x16, bf_, bi_, bc_, bo_,
                                                      hbuf, Cws, t);
    lstm_out<<<dim3(256), dim3(256), 0, stream>>>(hbuf, Wlin, blin, out);
  } else if (ws_size >= needB) {
    _Float16* W16  = (_Float16*)d_ws;
    _Float16* hbuf = (_Float16*)((char*)d_ws + offH);
    float*    Cws  = (float*)((char*)d_ws + offC);
    prep_w<<<dim3(64 * 2 * 24), dim3(64), 0, stream>>>(Wf, Wi, Wc, Wo, W16);
    for (int t = 0; t < TT; ++t)
      lstm_stepB<<<dim3(256), dim3(256), 0, stream>>>(W16, x, bf_, bi_, bc_, bo_,
                                                      hbuf, Cws, t);
    lstm_out<<<dim3(256), dim3(256), 0, stream>>>(hbuf, Wlin, blin, out);
  } else {
    _Float16* hbuf = (_Float16*)d_ws;                              // 256 KB
    float*    Cws  = (float*)((char*)d_ws + (size_t)2 * BB * HH * 2);
    for (int t = 0; t < TT; ++t)
      lstm_stepC<<<dim3(256), dim3(256), 0, stream>>>(x, Wf, Wi, Wc, Wo,
                                                      bf_, bi_, bc_, bo_,
                                                      hbuf, Cws, t);
    lstm_out<<<dim3(256), dim3(256), 0, stream>>>(hbuf, Wlin, blin, out);
  }
}